// Round 2
// baseline (497.829 us; speedup 1.0000x reference)
//
#include <hip/hip_runtime.h>
#include <hip/hip_bf16.h>

// N=8192 rows, BD=64 code dim, CD=512 channel dim
#define NN 8192
#define BD 64
#define CDIM 512

typedef __attribute__((ext_vector_type(4))) float f32x4;
typedef __attribute__((ext_vector_type(4))) unsigned int u32x4;
typedef __attribute__((ext_vector_type(8))) __bf16 bf16x8;

static __device__ __forceinline__ unsigned short f2bf(float x) {
    unsigned int u = __float_as_uint(x);
    u += 0x7fffu + ((u >> 16) & 1u);   // RTNE (inputs are finite, no NaN handling needed)
    return (unsigned short)(u >> 16);
}

static __device__ __forceinline__ f32x4 mfma16(u32x4 a, u32x4 b, f32x4 c) {
    return __builtin_amdgcn_mfma_f32_16x16x32_bf16(
        __builtin_bit_cast(bf16x8, a), __builtin_bit_cast(bf16x8, b), c, 0, 0, 0);
}

// load 8 consecutive fp32 and pack to bf16x8 (as u32x4)
static __device__ __forceinline__ u32x4 cvt8(const float* __restrict__ p) {
    float4 a = *(const float4*)p;
    float4 b = *(const float4*)(p + 4);
    u32x4 r;
    r.x = (unsigned)f2bf(a.x) | ((unsigned)f2bf(a.y) << 16);
    r.y = (unsigned)f2bf(a.z) | ((unsigned)f2bf(a.w) << 16);
    r.z = (unsigned)f2bf(b.x) | ((unsigned)f2bf(b.y) << 16);
    r.w = (unsigned)f2bf(b.z) | ((unsigned)f2bf(b.w) << 16);
    return r;
}

// adj = (max(1 - |2*dot - si - sj|/64, 0))^1.4
static __device__ __forceinline__ float adj_fn(float dot, float sij) {
    float x = fabsf(fmaf(2.0f, dot, -sij));
    float base = fmaxf(fmaf(-0.015625f, x, 1.0f), 0.0f);
    // log2(0) = -inf -> exp2(-inf) = 0, matches pow(0,1.4)
    return exp2f(1.4f * __log2f(base));
}

// ---------------- prep: bbn -> bf16, row sums s ----------------
__global__ void prep_kernel(const float* __restrict__ bbn,
                            unsigned short* __restrict__ tbf,
                            float* __restrict__ s) {
    int gid = blockIdx.x * blockDim.x + threadIdx.x;  // 16 threads/row
    int row = gid >> 4;
    int part = gid & 15;
    float4 v = *(const float4*)(bbn + row * BD + part * 4);
    ushort4 o;
    o.x = f2bf(v.x); o.y = f2bf(v.y); o.z = f2bf(v.z); o.w = f2bf(v.w);
    *(ushort4*)(tbf + row * BD + part * 4) = o;
    float ps = v.x + v.y + v.z + v.w;
    ps += __shfl_xor(ps, 1); ps += __shfl_xor(ps, 2);
    ps += __shfl_xor(ps, 4); ps += __shfl_xor(ps, 8);
    if (part == 0) s[row] = ps;
}

// ---------------- deg: d[i] = sum_j adj[i][j] ----------------
__global__ __launch_bounds__(256) void deg_kernel(const unsigned short* __restrict__ tbf,
                                                  const float* __restrict__ s,
                                                  float* __restrict__ d) {
    const int lane = threadIdx.x & 63;
    const int wave = threadIdx.x >> 6;
    const int m = lane & 15, q = lane >> 4;
    const int i0 = blockIdx.x * 64;

    u32x4 afr[4][2];
    float si[4][4];
#pragma unroll
    for (int mt = 0; mt < 4; ++mt) {
#pragma unroll
        for (int ks = 0; ks < 2; ++ks)
            afr[mt][ks] = *(const u32x4*)(tbf + (i0 + mt * 16 + m) * BD + ks * 32 + q * 8);
#pragma unroll
        for (int r = 0; r < 4; ++r) si[mt][r] = s[i0 + mt * 16 + q * 4 + r];
    }
    float dsum[4][4] = {};

    const int jbase = blockIdx.y * 2048 + wave * 512;
    for (int jt = 0; jt < 512; jt += 16) {
        int j0 = jbase + jt;
        u32x4 b0 = *(const u32x4*)(tbf + (j0 + m) * BD + q * 8);
        u32x4 b1 = *(const u32x4*)(tbf + (j0 + m) * BD + 32 + q * 8);
        float sj = s[j0 + m];
#pragma unroll
        for (int mt = 0; mt < 4; ++mt) {
            f32x4 c = {0.f, 0.f, 0.f, 0.f};
            c = mfma16(afr[mt][0], b0, c);
            c = mfma16(afr[mt][1], b1, c);
#pragma unroll
            for (int r = 0; r < 4; ++r)
                dsum[mt][r] += adj_fn(c[r], si[mt][r] + sj);
        }
    }
#pragma unroll
    for (int mt = 0; mt < 4; ++mt)
#pragma unroll
        for (int r = 0; r < 4; ++r) {
            float v = dsum[mt][r];
            v += __shfl_xor(v, 1); v += __shfl_xor(v, 2);
            v += __shfl_xor(v, 4); v += __shfl_xor(v, 8);
            if (m == 0) atomicAdd(&d[i0 + mt * 16 + q * 4 + r], v);
        }
}

// ---------------- dinv ----------------
__global__ void dinv_kernel(const float* __restrict__ d, float* __restrict__ dinv) {
    int i = blockIdx.x * 256 + threadIdx.x;
    dinv[i] = rsqrtf(d[i] + 1e-8f);
}

// ---------------- fc: fcT[k][i] = bf16(cbn @ W.T + b) ----------------
__global__ __launch_bounds__(256) void fc_kernel(const float* __restrict__ cbn,
                                                 const float* __restrict__ W,
                                                 const float* __restrict__ bias,
                                                 unsigned short* __restrict__ fcT) {
    const int lane = threadIdx.x & 63;
    const int wave = threadIdx.x >> 6;
    const int m = lane & 15, q = lane >> 4;
    const int i0 = blockIdx.x * 64;
    const int k0 = blockIdx.y * 64 + wave * 16;

    f32x4 acc[4] = {};
    for (int cs = 0; cs < CDIM; cs += 32) {
        u32x4 bfr = cvt8(W + (size_t)(k0 + m) * CDIM + cs + q * 8);
#pragma unroll
        for (int mt = 0; mt < 4; ++mt) {
            u32x4 afr = cvt8(cbn + (size_t)(i0 + mt * 16 + m) * CDIM + cs + q * 8);
            acc[mt] = mfma16(afr, bfr, acc[mt]);
        }
    }
    float bv = bias[k0 + m];
#pragma unroll
    for (int mt = 0; mt < 4; ++mt) {
        ushort4 o;
        o.x = f2bf(acc[mt][0] + bv);
        o.y = f2bf(acc[mt][1] + bv);
        o.z = f2bf(acc[mt][2] + bv);
        o.w = f2bf(acc[mt][3] + bv);
        *(ushort4*)(fcT + (size_t)(k0 + m) * NN + i0 + mt * 16 + q * 4) = o;
    }
}

// ---------------- conv: out = sigmoid(lap @ fc), flash-style ----------------
__global__ __launch_bounds__(256, 1) void conv_kernel(const unsigned short* __restrict__ tbf,
                                                      const unsigned short* __restrict__ fcT,
                                                      const float* __restrict__ s,
                                                      const float* __restrict__ dinv,
                                                      float* __restrict__ out) {
    const int lane = threadIdx.x & 63;
    const int wave = threadIdx.x >> 6;
    const int m = lane & 15, q = lane >> 4;
    const int i0 = blockIdx.x * 64;
    const int c0 = blockIdx.y * 256 + wave * 64;

    __shared__ __align__(16) unsigned short Slds[64][72];  // +8 pad: breaks 16-way bank conflict

    u32x4 afr[4][2];
    float si[4][4], dvi[4][4];
#pragma unroll
    for (int mt = 0; mt < 4; ++mt) {
#pragma unroll
        for (int ks = 0; ks < 2; ++ks)
            afr[mt][ks] = *(const u32x4*)(tbf + (i0 + mt * 16 + m) * BD + ks * 32 + q * 8);
#pragma unroll
        for (int r = 0; r < 4; ++r) {
            int row = i0 + mt * 16 + q * 4 + r;
            si[mt][r] = s[row];
            dvi[mt][r] = dinv[row];
        }
    }

    f32x4 acc[4][4] = {};

    for (int j0 = 0; j0 < NN; j0 += 64) {
        // ---- score tile S[64][64]: this wave computes cols [wave*16, wave*16+16)
        int jw = j0 + wave * 16;
        u32x4 b0 = *(const u32x4*)(tbf + (jw + m) * BD + q * 8);
        u32x4 b1 = *(const u32x4*)(tbf + (jw + m) * BD + 32 + q * 8);
        float sj = s[jw + m];
        float dvj = dinv[jw + m];
#pragma unroll
        for (int mt = 0; mt < 4; ++mt) {
            f32x4 c = {0.f, 0.f, 0.f, 0.f};
            c = mfma16(afr[mt][0], b0, c);
            c = mfma16(afr[mt][1], b1, c);
#pragma unroll
            for (int r = 0; r < 4; ++r) {
                float lap = adj_fn(c[r], si[mt][r] + sj) * dvi[mt][r] * dvj;
                Slds[mt * 16 + q * 4 + r][wave * 16 + m] = f2bf(lap);
            }
        }
        __syncthreads();
        // ---- PV: acc[64 rows][this wave's 64 cols] += S @ fc
#pragma unroll
        for (int ks = 0; ks < 2; ++ks) {
            u32x4 pa[4];
#pragma unroll
            for (int mt = 0; mt < 4; ++mt)
                pa[mt] = *(const u32x4*)(&Slds[mt * 16 + m][ks * 32 + q * 8]);
#pragma unroll
            for (int nt = 0; nt < 4; ++nt) {
                u32x4 bf = *(const u32x4*)(fcT + (size_t)(c0 + nt * 16 + m) * NN + j0 + ks * 32 + q * 8);
#pragma unroll
                for (int mt = 0; mt < 4; ++mt)
                    acc[mt][nt] = mfma16(pa[mt], bf, acc[mt][nt]);
            }
        }
        __syncthreads();
    }

#pragma unroll
    for (int mt = 0; mt < 4; ++mt)
#pragma unroll
        for (int nt = 0; nt < 4; ++nt)
#pragma unroll
            for (int r = 0; r < 4; ++r) {
                int row = i0 + mt * 16 + q * 4 + r;
                int col = c0 + nt * 16 + m;
                float x = acc[mt][nt][r];
                out[(size_t)row * CDIM + col] = 1.0f / (1.0f + __expf(-x));
            }
}

extern "C" void kernel_launch(void* const* d_in, const int* in_sizes, int n_in,
                              void* d_out, int out_size, void* d_ws, size_t ws_size,
                              hipStream_t stream) {
    const float* bbn = (const float*)d_in[0];
    const float* cbn = (const float*)d_in[1];
    const float* W   = (const float*)d_in[2];
    const float* b   = (const float*)d_in[3];
    float* out = (float*)d_out;  // reference output is float32

    char* ws = (char*)d_ws;
    unsigned short* tbf = (unsigned short*)(ws);                    // 8192*64*2  = 1 MB
    float* s            = (float*)(ws + 1048576);                   // 32 KB
    float* d            = (float*)(ws + 1048576 + 32768);           // 32 KB
    float* dinv         = (float*)(ws + 1048576 + 65536);           // 32 KB
    unsigned short* fcT = (unsigned short*)(ws + 1048576 + 98304);  // 512*8192*2 = 8 MB

    prep_kernel<<<NN * 16 / 256, 256, 0, stream>>>(bbn, tbf, s);
    hipMemsetAsync(d, 0, NN * sizeof(float), stream);
    deg_kernel<<<dim3(NN / 64, 4), 256, 0, stream>>>(tbf, s, d);
    dinv_kernel<<<NN / 256, 256, 0, stream>>>(d, dinv);
    fc_kernel<<<dim3(NN / 64, CDIM / 64), 256, 0, stream>>>(cbn, W, b, fcT);
    conv_kernel<<<dim3(NN / 64, 2), 256, 0, stream>>>(tbf, fcT, s, dinv, out);
}

// Round 3
// 435.418 us; speedup vs baseline: 1.1433x; 1.1433x over previous
//
#include <hip/hip_runtime.h>
#include <hip/hip_bf16.h>

// N=8192 rows, BD=64 code dim, CD=512 channel dim
#define NN 8192
#define BD 64
#define CDIM 512
#define JT 128   // conv j-tile per barrier pair

typedef __attribute__((ext_vector_type(4))) float f32x4;
typedef __attribute__((ext_vector_type(4))) unsigned int u32x4;
typedef __attribute__((ext_vector_type(8))) __bf16 bf16x8;

static __device__ __forceinline__ unsigned short f2bf(float x) {
    unsigned int u = __float_as_uint(x);
    u += 0x7fffu + ((u >> 16) & 1u);   // RTNE
    return (unsigned short)(u >> 16);
}

static __device__ __forceinline__ f32x4 mfma16(u32x4 a, u32x4 b, f32x4 c) {
    return __builtin_amdgcn_mfma_f32_16x16x32_bf16(
        __builtin_bit_cast(bf16x8, a), __builtin_bit_cast(bf16x8, b), c, 0, 0, 0);
}

// load 8 consecutive fp32 and pack to bf16x8 (as u32x4)
static __device__ __forceinline__ u32x4 cvt8(const float* __restrict__ p) {
    float4 a = *(const float4*)p;
    float4 b = *(const float4*)(p + 4);
    u32x4 r;
    r.x = (unsigned)f2bf(a.x) | ((unsigned)f2bf(a.y) << 16);
    r.y = (unsigned)f2bf(a.z) | ((unsigned)f2bf(a.w) << 16);
    r.z = (unsigned)f2bf(b.x) | ((unsigned)f2bf(b.y) << 16);
    r.w = (unsigned)f2bf(b.z) | ((unsigned)f2bf(b.w) << 16);
    return r;
}

// adj = (max(1 - |2*dot - si - sj|/64, 0))^1.4
static __device__ __forceinline__ float adj_fn(float dot, float sij) {
    float x = fabsf(fmaf(2.0f, dot, -sij));
    float base = fmaxf(fmaf(-0.015625f, x, 1.0f), 0.0f);
    // log2(0) = -inf -> exp2(-inf) = 0, matches pow(0,1.4)
    return exp2f(1.4f * __log2f(base));
}

// ---------------- prep: bbn -> bf16, row sums s ----------------
__global__ void prep_kernel(const float* __restrict__ bbn,
                            unsigned short* __restrict__ tbf,
                            float* __restrict__ s) {
    int gid = blockIdx.x * blockDim.x + threadIdx.x;  // 16 threads/row
    int row = gid >> 4;
    int part = gid & 15;
    float4 v = *(const float4*)(bbn + row * BD + part * 4);
    ushort4 o;
    o.x = f2bf(v.x); o.y = f2bf(v.y); o.z = f2bf(v.z); o.w = f2bf(v.w);
    *(ushort4*)(tbf + row * BD + part * 4) = o;
    float ps = v.x + v.y + v.z + v.w;
    ps += __shfl_xor(ps, 1); ps += __shfl_xor(ps, 2);
    ps += __shfl_xor(ps, 4); ps += __shfl_xor(ps, 8);
    if (part == 0) s[row] = ps;
}

// ---------------- deg: d[i] = sum_j adj[i][j] ----------------
__global__ __launch_bounds__(256) void deg_kernel(const unsigned short* __restrict__ tbf,
                                                  const float* __restrict__ s,
                                                  float* __restrict__ d) {
    const int lane = threadIdx.x & 63;
    const int wave = threadIdx.x >> 6;
    const int m = lane & 15, q = lane >> 4;
    const int i0 = blockIdx.x * 64;

    u32x4 afr[4][2];
    float si[4][4];
#pragma unroll
    for (int mt = 0; mt < 4; ++mt) {
#pragma unroll
        for (int ks = 0; ks < 2; ++ks)
            afr[mt][ks] = *(const u32x4*)(tbf + (i0 + mt * 16 + m) * BD + ks * 32 + q * 8);
#pragma unroll
        for (int r = 0; r < 4; ++r) si[mt][r] = s[i0 + mt * 16 + q * 4 + r];
    }
    float dsum[4][4] = {};

    const int jbase = blockIdx.y * 1024 + wave * 256;
    for (int jt = 0; jt < 256; jt += 16) {
        int j0 = jbase + jt;
        u32x4 b0 = *(const u32x4*)(tbf + (j0 + m) * BD + q * 8);
        u32x4 b1 = *(const u32x4*)(tbf + (j0 + m) * BD + 32 + q * 8);
        float sj = s[j0 + m];
#pragma unroll
        for (int mt = 0; mt < 4; ++mt) {
            f32x4 c = {0.f, 0.f, 0.f, 0.f};
            c = mfma16(afr[mt][0], b0, c);
            c = mfma16(afr[mt][1], b1, c);
#pragma unroll
            for (int r = 0; r < 4; ++r)
                dsum[mt][r] += adj_fn(c[r], si[mt][r] + sj);
        }
    }
#pragma unroll
    for (int mt = 0; mt < 4; ++mt)
#pragma unroll
        for (int r = 0; r < 4; ++r) {
            float v = dsum[mt][r];
            v += __shfl_xor(v, 1); v += __shfl_xor(v, 2);
            v += __shfl_xor(v, 4); v += __shfl_xor(v, 8);
            if (m == 0) atomicAdd(&d[i0 + mt * 16 + q * 4 + r], v);
        }
}

// ---------------- dinv ----------------
__global__ void dinv_kernel(const float* __restrict__ d, float* __restrict__ dinv) {
    int i = blockIdx.x * 256 + threadIdx.x;
    dinv[i] = rsqrtf(d[i] + 1e-8f);
}

// ---------------- fc: fc2T[k][i] = bf16(dinv[i] * (cbn @ W.T + b)) ----------------
__global__ __launch_bounds__(256) void fc_kernel(const float* __restrict__ cbn,
                                                 const float* __restrict__ W,
                                                 const float* __restrict__ bias,
                                                 const float* __restrict__ dinv,
                                                 unsigned short* __restrict__ fc2T) {
    const int lane = threadIdx.x & 63;
    const int wave = threadIdx.x >> 6;
    const int m = lane & 15, q = lane >> 4;
    const int i0 = blockIdx.x * 64;
    const int k0 = blockIdx.y * 64 + wave * 16;

    f32x4 acc[4] = {};
    for (int cs = 0; cs < CDIM; cs += 32) {
        u32x4 bfr = cvt8(W + (size_t)(k0 + m) * CDIM + cs + q * 8);
#pragma unroll
        for (int mt = 0; mt < 4; ++mt) {
            u32x4 afr = cvt8(cbn + (size_t)(i0 + mt * 16 + m) * CDIM + cs + q * 8);
            acc[mt] = mfma16(afr, bfr, acc[mt]);
        }
    }
    float bv = bias[k0 + m];
#pragma unroll
    for (int mt = 0; mt < 4; ++mt) {
        ushort4 o;
        // fold D^{-1/2} (right side) into fc: fc2[i] = dinv[i] * fc[i]
        o.x = f2bf((acc[mt][0] + bv) * dinv[i0 + mt * 16 + q * 4 + 0]);
        o.y = f2bf((acc[mt][1] + bv) * dinv[i0 + mt * 16 + q * 4 + 1]);
        o.z = f2bf((acc[mt][2] + bv) * dinv[i0 + mt * 16 + q * 4 + 2]);
        o.w = f2bf((acc[mt][3] + bv) * dinv[i0 + mt * 16 + q * 4 + 3]);
        *(ushort4*)(fc2T + (size_t)(k0 + m) * NN + i0 + mt * 16 + q * 4) = o;
    }
}

// ---------------- conv: out = sigmoid(dvi * (adj @ fc2)), flash-style ----------------
// 512 threads = 8 waves: 2 waves/SIMD. i-tile 64, c-tile 256 (32 cols/wave), j-tile 128.
__global__ __launch_bounds__(512, 2) void conv_kernel(const unsigned short* __restrict__ tbf,
                                                      const unsigned short* __restrict__ fc2T,
                                                      const float* __restrict__ s,
                                                      const float* __restrict__ dinv,
                                                      float* __restrict__ out) {
    const int lane = threadIdx.x & 63;
    const int wave = threadIdx.x >> 6;   // 0..7
    const int m = lane & 15, q = lane >> 4;
    // XCD swizzle: xcd = bid%8; xcds 0-3 -> col-half 0, 4-7 -> col-half 1.
    // Keeps each XCD's fc2T working set at 4 MB (~= its L2).
    const int bid = blockIdx.x;
    const int y = (bid >> 2) & 1;
    const int x = (bid >> 3) * 4 + (bid & 3);
    const int i0 = x * 64;
    const int cw = y * 256 + wave * 32;  // this wave's 32 output cols

    __shared__ __align__(16) unsigned short Slds[64][JT + 8];  // pad 8: conflict-free b128 reads

    u32x4 afr[4][2];
    float si[4][4];
#pragma unroll
    for (int mt = 0; mt < 4; ++mt) {
#pragma unroll
        for (int ks = 0; ks < 2; ++ks)
            afr[mt][ks] = *(const u32x4*)(tbf + (i0 + mt * 16 + m) * BD + ks * 32 + q * 8);
#pragma unroll
        for (int r = 0; r < 4; ++r) si[mt][r] = s[i0 + mt * 16 + q * 4 + r];
    }

    f32x4 acc[4][2] = {};

    for (int j0 = 0; j0 < NN; j0 += JT) {
        // ---- score: wave w computes adj cols [w*16, w*16+16) of this 64x128 tile
        int jw = j0 + wave * 16;
        u32x4 b0 = *(const u32x4*)(tbf + (jw + m) * BD + q * 8);
        u32x4 b1 = *(const u32x4*)(tbf + (jw + m) * BD + 32 + q * 8);
        float sj = s[jw + m];
#pragma unroll
        for (int mt = 0; mt < 4; ++mt) {
            f32x4 c = {0.f, 0.f, 0.f, 0.f};
            c = mfma16(afr[mt][0], b0, c);
            c = mfma16(afr[mt][1], b1, c);
#pragma unroll
            for (int r = 0; r < 4; ++r)
                Slds[mt * 16 + q * 4 + r][wave * 16 + m] = f2bf(adj_fn(c[r], si[mt][r] + sj));
        }
        __syncthreads();
        // ---- PV: acc[64 rows][this wave's 32 cols] += S @ fc2
#pragma unroll
        for (int ks = 0; ks < 4; ++ks) {
            u32x4 pa[4];
#pragma unroll
            for (int mt = 0; mt < 4; ++mt)
                pa[mt] = *(const u32x4*)(&Slds[mt * 16 + m][ks * 32 + q * 8]);
#pragma unroll
            for (int nt = 0; nt < 2; ++nt) {
                u32x4 bf = *(const u32x4*)(fc2T + (size_t)(cw + nt * 16 + m) * NN + j0 + ks * 32 + q * 8);
#pragma unroll
                for (int mt = 0; mt < 4; ++mt)
                    acc[mt][nt] = mfma16(pa[mt], bf, acc[mt][nt]);
            }
        }
        __syncthreads();
    }

#pragma unroll
    for (int mt = 0; mt < 4; ++mt)
#pragma unroll
        for (int r = 0; r < 4; ++r) {
            int row = i0 + mt * 16 + q * 4 + r;
            float dv = dinv[row];
#pragma unroll
            for (int nt = 0; nt < 2; ++nt) {
                int col = cw + nt * 16 + m;
                float xv = acc[mt][nt][r] * dv;
                out[(size_t)row * CDIM + col] = 1.0f / (1.0f + __expf(-xv));
            }
        }
}

extern "C" void kernel_launch(void* const* d_in, const int* in_sizes, int n_in,
                              void* d_out, int out_size, void* d_ws, size_t ws_size,
                              hipStream_t stream) {
    const float* bbn = (const float*)d_in[0];
    const float* cbn = (const float*)d_in[1];
    const float* W   = (const float*)d_in[2];
    const float* b   = (const float*)d_in[3];
    float* out = (float*)d_out;  // reference output is float32

    char* ws = (char*)d_ws;
    unsigned short* tbf  = (unsigned short*)(ws);                    // 8192*64*2  = 1 MB
    float* s             = (float*)(ws + 1048576);                   // 32 KB
    float* d             = (float*)(ws + 1048576 + 32768);           // 32 KB
    float* dinv          = (float*)(ws + 1048576 + 65536);           // 32 KB
    unsigned short* fc2T = (unsigned short*)(ws + 1048576 + 98304);  // 512*8192*2 = 8 MB

    prep_kernel<<<NN * 16 / 256, 256, 0, stream>>>(bbn, tbf, s);
    hipMemsetAsync(d, 0, NN * sizeof(float), stream);
    deg_kernel<<<dim3(NN / 64, 8), 256, 0, stream>>>(tbf, s, d);
    dinv_kernel<<<NN / 256, 256, 0, stream>>>(d, dinv);
    fc_kernel<<<dim3(NN / 64, CDIM / 64), 256, 0, stream>>>(cbn, W, b, dinv, fc2T);
    conv_kernel<<<256, 512, 0, stream>>>(tbf, fc2T, s, dinv, out);
}

// Round 4
// 398.827 us; speedup vs baseline: 1.2482x; 1.0917x over previous
//
#include <hip/hip_runtime.h>
#include <hip/hip_bf16.h>

// N=8192 rows, BD=64 code dim, CD=512 channel dim
#define NN 8192
#define BD 64
#define CDIM 512

typedef __attribute__((ext_vector_type(4))) float f32x4;
typedef __attribute__((ext_vector_type(4))) unsigned int u32x4;
typedef __attribute__((ext_vector_type(8))) __bf16 bf16x8;

static __device__ __forceinline__ unsigned short f2bf(float x) {
    unsigned int u = __float_as_uint(x);
    u += 0x7fffu + ((u >> 16) & 1u);   // RTNE
    return (unsigned short)(u >> 16);
}

static __device__ __forceinline__ f32x4 mfma16(u32x4 a, u32x4 b, f32x4 c) {
    return __builtin_amdgcn_mfma_f32_16x16x32_bf16(
        __builtin_bit_cast(bf16x8, a), __builtin_bit_cast(bf16x8, b), c, 0, 0, 0);
}

// load 8 consecutive fp32 and pack to bf16x8 (as u32x4)
static __device__ __forceinline__ u32x4 cvt8(const float* __restrict__ p) {
    float4 a = *(const float4*)p;
    float4 b = *(const float4*)(p + 4);
    u32x4 r;
    r.x = (unsigned)f2bf(a.x) | ((unsigned)f2bf(a.y) << 16);
    r.y = (unsigned)f2bf(a.z) | ((unsigned)f2bf(a.w) << 16);
    r.z = (unsigned)f2bf(b.x) | ((unsigned)f2bf(b.y) << 16);
    r.w = (unsigned)f2bf(b.z) | ((unsigned)f2bf(b.w) << 16);
    return r;
}

// adj = (max(1 - |2*dot - si - sj|/64, 0))^1.4
static __device__ __forceinline__ float adj_fn(float dot, float sij) {
    float x = fabsf(fmaf(2.0f, dot, -sij));
    float base = fmaxf(fmaf(-0.015625f, x, 1.0f), 0.0f);
    // log2(0) = -inf -> exp2(-inf) = 0, matches pow(0,1.4)
    return exp2f(1.4f * __log2f(base));
}

// ---------------- prep: bbn -> bf16, row sums s ----------------
__global__ void prep_kernel(const float* __restrict__ bbn,
                            unsigned short* __restrict__ tbf,
                            float* __restrict__ s) {
    int gid = blockIdx.x * blockDim.x + threadIdx.x;  // 16 threads/row
    int row = gid >> 4;
    int part = gid & 15;
    float4 v = *(const float4*)(bbn + row * BD + part * 4);
    ushort4 o;
    o.x = f2bf(v.x); o.y = f2bf(v.y); o.z = f2bf(v.z); o.w = f2bf(v.w);
    *(ushort4*)(tbf + row * BD + part * 4) = o;
    float ps = v.x + v.y + v.z + v.w;
    ps += __shfl_xor(ps, 1); ps += __shfl_xor(ps, 2);
    ps += __shfl_xor(ps, 4); ps += __shfl_xor(ps, 8);
    if (part == 0) s[row] = ps;
}

// ---------------- scoredeg: adjbf[i][j] = bf16(adj), d[i] = sum_j adj ----------------
// Computes each score tile ONCE (replaces the old deg kernel AND conv's recompute).
// grid (128 i-tiles, 8 j-chunks of 1024) = 1024 blocks -> 4 blocks/CU, 16 waves/CU.
__global__ __launch_bounds__(256) void scoredeg_kernel(const unsigned short* __restrict__ tbf,
                                                       const float* __restrict__ s,
                                                       float* __restrict__ d,
                                                       unsigned short* __restrict__ adjbf) {
    const int lane = threadIdx.x & 63;
    const int wave = threadIdx.x >> 6;   // 0..3
    const int m = lane & 15, q = lane >> 4;
    const int i0 = blockIdx.x * 64;
    const int jbase = blockIdx.y * 1024;

    __shared__ __align__(16) unsigned short Slds[64][72];  // 144B rows (16B mult), pad kills conflicts

    u32x4 afr[4][2];
    float si[4][4];
#pragma unroll
    for (int mt = 0; mt < 4; ++mt) {
#pragma unroll
        for (int ks = 0; ks < 2; ++ks)
            afr[mt][ks] = *(const u32x4*)(tbf + (i0 + mt * 16 + m) * BD + ks * 32 + q * 8);
#pragma unroll
        for (int r = 0; r < 4; ++r) si[mt][r] = s[i0 + mt * 16 + q * 4 + r];
    }
    float dsum[4][4] = {};

    const int t = threadIdx.x;
    const int rseg = t & 7;      // 8 x 16B segments per 128B row
    const int row0 = t >> 3;     // 32 rows per pass

    for (int jt = 0; jt < 1024; jt += 64) {
        // wave w computes adj cols [w*16, w*16+16) of this 64x64 tile
        int jw = jbase + jt + wave * 16;
        u32x4 b0 = *(const u32x4*)(tbf + (jw + m) * BD + q * 8);
        u32x4 b1 = *(const u32x4*)(tbf + (jw + m) * BD + 32 + q * 8);
        float sj = s[jw + m];
#pragma unroll
        for (int mt = 0; mt < 4; ++mt) {
            f32x4 c = {0.f, 0.f, 0.f, 0.f};
            c = mfma16(afr[mt][0], b0, c);
            c = mfma16(afr[mt][1], b1, c);
#pragma unroll
            for (int r = 0; r < 4; ++r) {
                float a = adj_fn(c[r], si[mt][r] + sj);
                dsum[mt][r] += a;
                Slds[mt * 16 + q * 4 + r][wave * 16 + m] = f2bf(a);
            }
        }
        __syncthreads();
        // cooperative coalesced store: 64 rows x 128B
#pragma unroll
        for (int pass = 0; pass < 2; ++pass) {
            int row = pass * 32 + row0;
            u32x4 v = *(const u32x4*)(&Slds[row][rseg * 8]);
            *(u32x4*)(adjbf + (size_t)(i0 + row) * NN + jbase + jt + rseg * 8) = v;
        }
        __syncthreads();
    }

#pragma unroll
    for (int mt = 0; mt < 4; ++mt)
#pragma unroll
        for (int r = 0; r < 4; ++r) {
            float v = dsum[mt][r];
            v += __shfl_xor(v, 1); v += __shfl_xor(v, 2);
            v += __shfl_xor(v, 4); v += __shfl_xor(v, 8);
            if (m == 0) atomicAdd(&d[i0 + mt * 16 + q * 4 + r], v);
        }
}

// ---------------- dinv ----------------
__global__ void dinv_kernel(const float* __restrict__ d, float* __restrict__ dinv) {
    int i = blockIdx.x * 256 + threadIdx.x;
    dinv[i] = rsqrtf(d[i] + 1e-8f);
}

// ---------------- fc: fc2T[k][i] = bf16(dinv[i] * (cbn @ W.T + b)) ----------------
__global__ __launch_bounds__(256) void fc_kernel(const float* __restrict__ cbn,
                                                 const float* __restrict__ W,
                                                 const float* __restrict__ bias,
                                                 const float* __restrict__ dinv,
                                                 unsigned short* __restrict__ fc2T) {
    const int lane = threadIdx.x & 63;
    const int wave = threadIdx.x >> 6;
    const int m = lane & 15, q = lane >> 4;
    const int i0 = blockIdx.x * 64;
    const int k0 = blockIdx.y * 64 + wave * 16;

    f32x4 acc[4] = {};
    for (int cs = 0; cs < CDIM; cs += 32) {
        u32x4 bfr = cvt8(W + (size_t)(k0 + m) * CDIM + cs + q * 8);
#pragma unroll
        for (int mt = 0; mt < 4; ++mt) {
            u32x4 afr = cvt8(cbn + (size_t)(i0 + mt * 16 + m) * CDIM + cs + q * 8);
            acc[mt] = mfma16(afr, bfr, acc[mt]);
        }
    }
    float bv = bias[k0 + m];
#pragma unroll
    for (int mt = 0; mt < 4; ++mt) {
        ushort4 o;
        o.x = f2bf((acc[mt][0] + bv) * dinv[i0 + mt * 16 + q * 4 + 0]);
        o.y = f2bf((acc[mt][1] + bv) * dinv[i0 + mt * 16 + q * 4 + 1]);
        o.z = f2bf((acc[mt][2] + bv) * dinv[i0 + mt * 16 + q * 4 + 2]);
        o.w = f2bf((acc[mt][3] + bv) * dinv[i0 + mt * 16 + q * 4 + 3]);
        *(ushort4*)(fc2T + (size_t)(k0 + m) * NN + i0 + mt * 16 + q * 4) = o;
    }
}

// ---------------- conv2: out = sigmoid(dvi * (adjbf @ fc2)) — pure bf16 GEMM ----------------
// M=8192 N=512 K=8192. Tile 64x128, 4 waves (each 64 rows x 32 cols), K-chunk 64 staged in LDS.
// grid 512 = 2 blocks/CU. XCD swizzle: xcd pair shares one 128-col fc2T slice (2 MB, L2-resident).
__global__ __launch_bounds__(256) void conv2_kernel(const unsigned short* __restrict__ adjbf,
                                                    const unsigned short* __restrict__ fc2T,
                                                    const float* __restrict__ dinv,
                                                    float* __restrict__ out) {
    const int bid = blockIdx.x;
    const int xcd = bid & 7;
    const int cblk = xcd >> 1;                   // 0..3
    const int iblk = (bid >> 3) * 2 + (xcd & 1); // 0..127
    const int i0 = iblk * 64;

    const int lane = threadIdx.x & 63;
    const int wave = threadIdx.x >> 6;   // 0..3
    const int m = lane & 15, q = lane >> 4;
    const int cw = cblk * 128 + wave * 32;

    __shared__ __align__(16) unsigned short Alds[64][72];  // pad: 8 distinct bank groups for b128

    const int t = threadIdx.x;
    const int srow = t >> 2;     // 64 rows
    const int sseg = t & 3;      // 2 of 8 segs per thread (sseg, sseg+4)

    f32x4 acc[4][2] = {};

    for (int k0 = 0; k0 < NN; k0 += 64) {
        // stage A chunk (issue loads before barrier so they fly during it)
        const unsigned short* ap = adjbf + (size_t)(i0 + srow) * NN + k0 + sseg * 8;
        u32x4 v0 = *(const u32x4*)(ap);
        u32x4 v1 = *(const u32x4*)(ap + 32);
        __syncthreads();   // prior chunk's readers done
        *(u32x4*)(&Alds[srow][sseg * 8]) = v0;
        *(u32x4*)(&Alds[srow][32 + sseg * 8]) = v1;
        __syncthreads();
#pragma unroll
        for (int ks = 0; ks < 2; ++ks) {
            u32x4 pa[4];
#pragma unroll
            for (int mt = 0; mt < 4; ++mt)
                pa[mt] = *(const u32x4*)(&Alds[mt * 16 + m][ks * 32 + q * 8]);
#pragma unroll
            for (int nt = 0; nt < 2; ++nt) {
                u32x4 bf = *(const u32x4*)(fc2T + (size_t)(cw + nt * 16 + m) * NN + k0 + ks * 32 + q * 8);
#pragma unroll
                for (int mt = 0; mt < 4; ++mt)
                    acc[mt][nt] = mfma16(pa[mt], bf, acc[mt][nt]);
            }
        }
    }

#pragma unroll
    for (int mt = 0; mt < 4; ++mt)
#pragma unroll
        for (int r = 0; r < 4; ++r) {
            int row = i0 + mt * 16 + q * 4 + r;
            float dv = dinv[row];
#pragma unroll
            for (int nt = 0; nt < 2; ++nt) {
                float xv = acc[mt][nt][r] * dv;
                out[(size_t)row * CDIM + cw + nt * 16 + m] = 1.0f / (1.0f + __expf(-xv));
            }
        }
}

extern "C" void kernel_launch(void* const* d_in, const int* in_sizes, int n_in,
                              void* d_out, int out_size, void* d_ws, size_t ws_size,
                              hipStream_t stream) {
    const float* bbn = (const float*)d_in[0];
    const float* cbn = (const float*)d_in[1];
    const float* W   = (const float*)d_in[2];
    const float* b   = (const float*)d_in[3];
    float* out = (float*)d_out;  // reference output is float32

    char* ws = (char*)d_ws;
    unsigned short* tbf  = (unsigned short*)(ws);                    // 1 MB
    float* s             = (float*)(ws + (1 << 20));                 // 32 KB
    float* d             = (float*)(ws + (1 << 20) + 32768);         // 32 KB
    float* dinv          = (float*)(ws + (1 << 20) + 65536);         // 32 KB
    unsigned short* fc2T = (unsigned short*)(ws + (1 << 20) + 98304);// 8 MB
    unsigned short* adjbf= (unsigned short*)(ws + (16u << 20));      // 8192*8192*2 = 128 MiB

    prep_kernel<<<NN * 16 / 256, 256, 0, stream>>>(bbn, tbf, s);
    hipMemsetAsync(d, 0, NN * sizeof(float), stream);
    scoredeg_kernel<<<dim3(NN / 64, 8), 256, 0, stream>>>(tbf, s, d, adjbf);
    dinv_kernel<<<NN / 256, 256, 0, stream>>>(d, dinv);
    fc_kernel<<<dim3(NN / 64, CDIM / 64), 256, 0, stream>>>(cbn, W, b, dinv, fc2T);
    conv2_kernel<<<512, 256, 0, stream>>>(adjbf, fc2T, dinv, out);
}

// Round 5
// 326.589 us; speedup vs baseline: 1.5243x; 1.2212x over previous
//
#include <hip/hip_runtime.h>
#include <hip/hip_bf16.h>

// N=8192 rows, BD=64 code dim, CD=512 channel dim
#define NN 8192
#define BD 64
#define CDIM 512
#define KC 128   // conv2 k per chunk

typedef __attribute__((ext_vector_type(4))) float f32x4;
typedef __attribute__((ext_vector_type(4))) unsigned int u32x4;
typedef __attribute__((ext_vector_type(8))) __bf16 bf16x8;

// Fragment-major layouts (elems = unsigned short):
//  adjF frag(it,kt): it=i/16 in [0,512), kt=k/32 in [0,256)
//    offset = (it*256 + kt)*512 + lane*8 ; lane=q*16+m holds adj[it*16+m][kt*32+q*8 .. +7]
//  fcF  frag(nt,kt): nt=n/16 in [0,32), kt=k/32 in [0,256)
//    offset = (nt*256 + kt)*512 + lane*8 ; lane holds fc2[kt*32+q*8 .. +7][nt*16+m]

static __device__ __forceinline__ unsigned short f2bf(float x) {
    unsigned int u = __float_as_uint(x);
    u += 0x7fffu + ((u >> 16) & 1u);   // RTNE
    return (unsigned short)(u >> 16);
}

static __device__ __forceinline__ f32x4 mfma16(u32x4 a, u32x4 b, f32x4 c) {
    return __builtin_amdgcn_mfma_f32_16x16x32_bf16(
        __builtin_bit_cast(bf16x8, a), __builtin_bit_cast(bf16x8, b), c, 0, 0, 0);
}

static __device__ __forceinline__ u32x4 cvt8(const float* __restrict__ p) {
    float4 a = *(const float4*)p;
    float4 b = *(const float4*)(p + 4);
    u32x4 r;
    r.x = (unsigned)f2bf(a.x) | ((unsigned)f2bf(a.y) << 16);
    r.y = (unsigned)f2bf(a.z) | ((unsigned)f2bf(a.w) << 16);
    r.z = (unsigned)f2bf(b.x) | ((unsigned)f2bf(b.y) << 16);
    r.w = (unsigned)f2bf(b.z) | ((unsigned)f2bf(b.w) << 16);
    return r;
}

// adj = (max(1 - |2*dot - si - sj|/64, 0))^1.4
static __device__ __forceinline__ float adj_fn(float dot, float sij) {
    float x = fabsf(fmaf(2.0f, dot, -sij));
    float base = fmaxf(fmaf(-0.015625f, x, 1.0f), 0.0f);
    return exp2f(1.4f * __log2f(base));   // pow(0,1.4)=0 via -inf
}

// ---------------- prep: bbn -> bf16, row sums s ----------------
__global__ void prep_kernel(const float* __restrict__ bbn,
                            unsigned short* __restrict__ tbf,
                            float* __restrict__ s) {
    int gid = blockIdx.x * blockDim.x + threadIdx.x;  // 16 threads/row
    int row = gid >> 4;
    int part = gid & 15;
    float4 v = *(const float4*)(bbn + row * BD + part * 4);
    ushort4 o;
    o.x = f2bf(v.x); o.y = f2bf(v.y); o.z = f2bf(v.z); o.w = f2bf(v.w);
    *(ushort4*)(tbf + row * BD + part * 4) = o;
    float ps = v.x + v.y + v.z + v.w;
    ps += __shfl_xor(ps, 1); ps += __shfl_xor(ps, 2);
    ps += __shfl_xor(ps, 4); ps += __shfl_xor(ps, 8);
    if (part == 0) s[row] = ps;
}

// ---------------- scoredeg: adjF = frag-major bf16 adj, d[i] = row sums ----------------
__global__ __launch_bounds__(256) void scoredeg_kernel(const unsigned short* __restrict__ tbf,
                                                       const float* __restrict__ s,
                                                       float* __restrict__ d,
                                                       unsigned short* __restrict__ adjF) {
    const int lane = threadIdx.x & 63;
    const int wave = threadIdx.x >> 6;   // 0..3
    const int m = lane & 15, q = lane >> 4;
    const int i0 = blockIdx.x * 64;
    const int jbase = blockIdx.y * 1024;

    __shared__ __align__(16) unsigned short Slds[64][72];

    u32x4 afr[4][2];
    float si[4][4];
#pragma unroll
    for (int mt = 0; mt < 4; ++mt) {
#pragma unroll
        for (int ks = 0; ks < 2; ++ks)
            afr[mt][ks] = *(const u32x4*)(tbf + (i0 + mt * 16 + m) * BD + ks * 32 + q * 8);
#pragma unroll
        for (int r = 0; r < 4; ++r) si[mt][r] = s[i0 + mt * 16 + q * 4 + r];
    }
    float dsum[4][4] = {};

    for (int jt = 0; jt < 1024; jt += 64) {
        int J = jbase + jt;
        // wave w computes adj cols [w*16, w*16+16) of this 64x64 tile
        int jw = J + wave * 16;
        u32x4 b0 = *(const u32x4*)(tbf + (jw + m) * BD + q * 8);
        u32x4 b1 = *(const u32x4*)(tbf + (jw + m) * BD + 32 + q * 8);
        float sj = s[jw + m];
#pragma unroll
        for (int mt = 0; mt < 4; ++mt) {
            f32x4 c = {0.f, 0.f, 0.f, 0.f};
            c = mfma16(afr[mt][0], b0, c);
            c = mfma16(afr[mt][1], b1, c);
#pragma unroll
            for (int r = 0; r < 4; ++r) {
                float a = adj_fn(c[r], si[mt][r] + sj);
                dsum[mt][r] += a;
                Slds[mt * 16 + q * 4 + r][wave * 16 + m] = f2bf(a);
            }
        }
        __syncthreads();
        // store 8 fragments: wave w -> i-tile (i0/16 + w), k-tiles J/32 + {0,1}
#pragma unroll
        for (int ktl = 0; ktl < 2; ++ktl) {
            u32x4 v = *(const u32x4*)(&Slds[wave * 16 + m][ktl * 32 + q * 8]);
            *(u32x4*)(adjF + ((size_t)((i0 >> 4) + wave) * 256 + (J >> 5) + ktl) * 512 + lane * 8) = v;
        }
        __syncthreads();
    }

#pragma unroll
    for (int mt = 0; mt < 4; ++mt)
#pragma unroll
        for (int r = 0; r < 4; ++r) {
            float v = dsum[mt][r];
            v += __shfl_xor(v, 1); v += __shfl_xor(v, 2);
            v += __shfl_xor(v, 4); v += __shfl_xor(v, 8);
            if (m == 0) atomicAdd(&d[i0 + mt * 16 + q * 4 + r], v);
        }
}

// ---------------- dinv ----------------
__global__ void dinv_kernel(const float* __restrict__ d, float* __restrict__ dinv) {
    int i = blockIdx.x * 256 + threadIdx.x;
    dinv[i] = rsqrtf(d[i] + 1e-8f);
}

// ---------------- fc: fcF = frag-major bf16(dinv[i]*(cbn @ W.T + b)) ----------------
__global__ __launch_bounds__(256) void fc_kernel(const float* __restrict__ cbn,
                                                 const float* __restrict__ W,
                                                 const float* __restrict__ bias,
                                                 const float* __restrict__ dinv,
                                                 unsigned short* __restrict__ fcF) {
    const int lane = threadIdx.x & 63;
    const int wave = threadIdx.x >> 6;
    const int m = lane & 15, q = lane >> 4;
    const int i0 = blockIdx.x * 64;
    const int k0 = blockIdx.y * 64 + wave * 16;   // output col tile (n)

    f32x4 acc[4] = {};
    for (int cs = 0; cs < CDIM; cs += 32) {
        u32x4 bfr = cvt8(W + (size_t)(k0 + m) * CDIM + cs + q * 8);
#pragma unroll
        for (int mt = 0; mt < 4; ++mt) {
            u32x4 afr = cvt8(cbn + (size_t)(i0 + mt * 16 + m) * CDIM + cs + q * 8);
            acc[mt] = mfma16(afr, bfr, acc[mt]);
        }
    }
    float bv = bias[k0 + m];
#pragma unroll
    for (int mt = 0; mt < 4; ++mt) {
        int i = i0 + mt * 16 + q * 4;   // k-dim index of conv2 (fc row)
        ushort4 o;
        o.x = f2bf((acc[mt][0] + bv) * dinv[i + 0]);
        o.y = f2bf((acc[mt][1] + bv) * dinv[i + 1]);
        o.z = f2bf((acc[mt][2] + bv) * dinv[i + 2]);
        o.w = f2bf((acc[mt][3] + bv) * dinv[i + 3]);
        // fcF addr: frag(nt=k0/16, kt=i/32), sub-k q'=(i>>3)&3, col m, elem i&7
        size_t off = ((size_t)(k0 >> 4) * 256 + (i >> 5)) * 512
                   + (size_t)((i >> 3) & 3) * 128 + m * 8 + (q & 1) * 4;
        *(ushort4*)(fcF + off) = o;
    }
}

// ---------------- conv2: out = sigmoid(dvi * (adj @ fc2)) — frag-major GEMM ----------------
// M=8192 N=512 K=8192. Block: 64 rows x 128 cols, 4 waves (64x32 each).
// k-chunk 128 staged in double-buffered LDS (identity frag layout, conflict-free).
// grid 512 = 2 blocks/CU; XCD pairs share one 128-col fcF slice (2 MB, L2-resident).
__global__ __launch_bounds__(256) void conv2_kernel(const unsigned short* __restrict__ adjF,
                                                    const unsigned short* __restrict__ fcF,
                                                    const float* __restrict__ dinv,
                                                    float* __restrict__ out) {
    const int bid = blockIdx.x;
    const int xcd = bid & 7;
    const int cblk = xcd >> 1;                   // 0..3
    const int iblk = (bid >> 3) * 2 + (xcd & 1); // 0..127
    const int i0 = iblk * 64;

    const int lane = threadIdx.x & 63;
    const int wave = threadIdx.x >> 6;   // 0..3
    const int m = lane & 15, q = lane >> 4;
    const int cw = cblk * 128 + wave * 32;

    __shared__ __align__(16) unsigned short Abuf[2][KC / 32][4][512];  // 32 KB, identity frag layout

    const u32x4* Ag = (const u32x4*)adjF;   // frag = 64 u32x4
    const u32x4* Bg = (const u32x4*)fcF;
    const int itw = (i0 >> 4) + wave;       // this wave stages mt = wave
    const int ntb = cw >> 4;

    f32x4 acc[4][2] = {};
    u32x4 st[4];

    // prologue: stage chunk 0
#pragma unroll
    for (int ktl = 0; ktl < 4; ++ktl)
        st[ktl] = Ag[((size_t)itw * 256 + ktl) * 64 + lane];
#pragma unroll
    for (int ktl = 0; ktl < 4; ++ktl)
        *(u32x4*)&Abuf[0][ktl][wave][lane * 8] = st[ktl];
    __syncthreads();

    for (int c = 0; c < NN / KC; ++c) {
        const int kb = c * (KC / 32);
        const int cur = c & 1, nxt = cur ^ 1;
        // prefetch next A chunk into regs (full MFMA phase to cover latency)
        const int kbn = (c + 1 < NN / KC) ? kb + (KC / 32) : kb;
#pragma unroll
        for (int ktl = 0; ktl < 4; ++ktl)
            st[ktl] = Ag[((size_t)itw * 256 + kbn + ktl) * 64 + lane];
        // consume current chunk
#pragma unroll
        for (int ktl = 0; ktl < 4; ++ktl) {
            u32x4 pa[4];
#pragma unroll
            for (int mt = 0; mt < 4; ++mt)
                pa[mt] = *(const u32x4*)&Abuf[cur][ktl][mt][lane * 8];
#pragma unroll
            for (int nt = 0; nt < 2; ++nt) {
                u32x4 bf = Bg[((size_t)(ntb + nt) * 256 + kb + ktl) * 64 + lane];
#pragma unroll
                for (int mt = 0; mt < 4; ++mt)
                    acc[mt][nt] = mfma16(pa[mt], bf, acc[mt][nt]);
            }
        }
        // publish next chunk
#pragma unroll
        for (int ktl = 0; ktl < 4; ++ktl)
            *(u32x4*)&Abuf[nxt][ktl][wave][lane * 8] = st[ktl];
        __syncthreads();
    }

#pragma unroll
    for (int mt = 0; mt < 4; ++mt)
#pragma unroll
        for (int r = 0; r < 4; ++r) {
            int row = i0 + mt * 16 + q * 4 + r;
            float dv = dinv[row];
#pragma unroll
            for (int nt = 0; nt < 2; ++nt) {
                float xv = acc[mt][nt][r] * dv;
                out[(size_t)row * CDIM + cw + nt * 16 + m] = 1.0f / (1.0f + __expf(-xv));
            }
        }
}

extern "C" void kernel_launch(void* const* d_in, const int* in_sizes, int n_in,
                              void* d_out, int out_size, void* d_ws, size_t ws_size,
                              hipStream_t stream) {
    const float* bbn = (const float*)d_in[0];
    const float* cbn = (const float*)d_in[1];
    const float* W   = (const float*)d_in[2];
    const float* b   = (const float*)d_in[3];
    float* out = (float*)d_out;  // reference output is float32

    char* ws = (char*)d_ws;
    unsigned short* tbf = (unsigned short*)(ws);                    // 1 MB
    float* s            = (float*)(ws + (1 << 20));                 // 32 KB
    float* d            = (float*)(ws + (1 << 20) + 32768);         // 32 KB
    float* dinv         = (float*)(ws + (1 << 20) + 65536);         // 32 KB
    unsigned short* fcF = (unsigned short*)(ws + (1 << 20) + 98304);// 8 MB
    unsigned short* adjF= (unsigned short*)(ws + (16u << 20));      // 128 MiB

    prep_kernel<<<NN * 16 / 256, 256, 0, stream>>>(bbn, tbf, s);
    hipMemsetAsync(d, 0, NN * sizeof(float), stream);
    scoredeg_kernel<<<dim3(NN / 64, 8), 256, 0, stream>>>(tbf, s, d, adjF);
    dinv_kernel<<<NN / 256, 256, 0, stream>>>(d, dinv);
    fc_kernel<<<dim3(NN / 64, CDIM / 64), 256, 0, stream>>>(cbn, W, b, dinv, fcF);
    conv2_kernel<<<512, 256, 0, stream>>>(adjF, fcF, dinv, out);
}

// Round 6
// 242.359 us; speedup vs baseline: 2.0541x; 1.3475x over previous
//
#include <hip/hip_runtime.h>
#include <hip/hip_bf16.h>

// N=8192 rows, BD=64 code dim, CD=512 channel dim
#define NN 8192
#define BD 64
#define CDIM 512
#define KC 128   // conv2 k per chunk

typedef __attribute__((ext_vector_type(4))) float f32x4;
typedef __attribute__((ext_vector_type(4))) unsigned int u32x4;
typedef __attribute__((ext_vector_type(8))) __bf16 bf16x8;

// Fragment-major layouts (elems = unsigned short), frag = 512 ushorts = 1 KB:
//  adjF frag(it,kt): it=i/16 [0,512), kt=k/32 [0,256): off=(it*256+kt)*512+lane*8
//    lane=q*16+m holds adj[it*16+m][kt*32+q*8 .. +7]   (A-operand layout)
//  fcF  frag(nt,kt): nt=n/16 [0,32), kt=k/32 [0,256):  off=(nt*256+kt)*512+lane*8
//    lane holds fc2[kt*32+q*8 .. +7][nt*16+m]          (B-operand layout)
//  cbnF frag(it,ct): it=i/16 [0,512), ct=c/32 [0,16):  off=(it*16+ct)*512+lane*8  (A)
//  WF   frag(nt,ct): nt=n/16 [0,32),  ct=c/32 [0,16):  off=(nt*16+ct)*512+lane*8  (B)

static __device__ __forceinline__ unsigned short f2bf(float x) {
    unsigned int u = __float_as_uint(x);
    u += 0x7fffu + ((u >> 16) & 1u);   // RTNE
    return (unsigned short)(u >> 16);
}

static __device__ __forceinline__ f32x4 mfma16(u32x4 a, u32x4 b, f32x4 c) {
    return __builtin_amdgcn_mfma_f32_16x16x32_bf16(
        __builtin_bit_cast(bf16x8, a), __builtin_bit_cast(bf16x8, b), c, 0, 0, 0);
}

static __device__ __forceinline__ u32x4 cvt8(const float* __restrict__ p) {
    float4 a = *(const float4*)p;
    float4 b = *(const float4*)(p + 4);
    u32x4 r;
    r.x = (unsigned)f2bf(a.x) | ((unsigned)f2bf(a.y) << 16);
    r.y = (unsigned)f2bf(a.z) | ((unsigned)f2bf(a.w) << 16);
    r.z = (unsigned)f2bf(b.x) | ((unsigned)f2bf(b.y) << 16);
    r.w = (unsigned)f2bf(b.z) | ((unsigned)f2bf(b.w) << 16);
    return r;
}

// adj = (max(1 - |2*dot - si - sj|/64, 0))^1.4
static __device__ __forceinline__ float adj_fn(float dot, float sij) {
    float x = fabsf(fmaf(2.0f, dot, -sij));
    float base = fmaxf(fmaf(-0.015625f, x, 1.0f), 0.0f);
    return exp2f(1.4f * __log2f(base));   // pow(0,1.4)=0 via -inf
}

// ---------------- prep: bbn -> bf16 (row-major), row sums s ----------------
__global__ void prep_kernel(const float* __restrict__ bbn,
                            unsigned short* __restrict__ tbf,
                            float* __restrict__ s) {
    int gid = blockIdx.x * blockDim.x + threadIdx.x;  // 16 threads/row
    int row = gid >> 4;
    int part = gid & 15;
    float4 v = *(const float4*)(bbn + row * BD + part * 4);
    ushort4 o;
    o.x = f2bf(v.x); o.y = f2bf(v.y); o.z = f2bf(v.z); o.w = f2bf(v.w);
    *(ushort4*)(tbf + row * BD + part * 4) = o;
    float ps = v.x + v.y + v.z + v.w;
    ps += __shfl_xor(ps, 1); ps += __shfl_xor(ps, 2);
    ps += __shfl_xor(ps, 4); ps += __shfl_xor(ps, 8);
    if (part == 0) s[row] = ps;
}

// ---------------- prep_cbn: cbn -> A-frag-major bf16 ----------------
__global__ __launch_bounds__(256) void prep_cbn_kernel(const float* __restrict__ cbn,
                                                       unsigned short* __restrict__ cbnF) {
    const int lane = threadIdx.x & 63;
    const int wave = threadIdx.x >> 6;
    const int m = lane & 15, q = lane >> 4;
#pragma unroll
    for (int t = 0; t < 4; ++t) {
        int f = blockIdx.x * 16 + wave * 4 + t;   // 8192 frags
        int it = f >> 4, ct = f & 15;
        u32x4 v = cvt8(cbn + (size_t)(it * 16 + m) * CDIM + ct * 32 + q * 8);
        *(u32x4*)(cbnF + (size_t)f * 512 + lane * 8) = v;
    }
}

// ---------------- prep_w: W -> B-frag-major bf16 (B[c][n] = W[n][c]) ----------------
__global__ __launch_bounds__(256) void prep_w_kernel(const float* __restrict__ W,
                                                     unsigned short* __restrict__ WF) {
    const int lane = threadIdx.x & 63;
    const int wave = threadIdx.x >> 6;
    const int m = lane & 15, q = lane >> 4;
    int f = blockIdx.x * 4 + wave;   // 512 frags
    int nt = f >> 4, ct = f & 15;
    u32x4 v = cvt8(W + (size_t)(nt * 16 + m) * CDIM + ct * 32 + q * 8);
    *(u32x4*)(WF + (size_t)f * 512 + lane * 8) = v;
}

// ---------------- scoredeg: adjF = frag-major bf16 adj, d[i] = row sums ----------------
// grid (128 i-tiles, 16 j-chunks of 512) = 2048 blocks -> 8 blocks/CU.
__global__ __launch_bounds__(256) void scoredeg_kernel(const unsigned short* __restrict__ tbf,
                                                       const float* __restrict__ s,
                                                       float* __restrict__ d,
                                                       unsigned short* __restrict__ adjF) {
    const int lane = threadIdx.x & 63;
    const int wave = threadIdx.x >> 6;   // 0..3
    const int m = lane & 15, q = lane >> 4;
    const int i0 = blockIdx.x * 64;
    const int jbase = blockIdx.y * 512;

    __shared__ __align__(16) unsigned short Slds[64][72];

    u32x4 afr[4][2];
    float si[4][4];
#pragma unroll
    for (int mt = 0; mt < 4; ++mt) {
#pragma unroll
        for (int ks = 0; ks < 2; ++ks)
            afr[mt][ks] = *(const u32x4*)(tbf + (i0 + mt * 16 + m) * BD + ks * 32 + q * 8);
#pragma unroll
        for (int r = 0; r < 4; ++r) si[mt][r] = s[i0 + mt * 16 + q * 4 + r];
    }
    float dsum[4][4] = {};

    for (int jt = 0; jt < 512; jt += 64) {
        int J = jbase + jt;
        int jw = J + wave * 16;
        u32x4 b0 = *(const u32x4*)(tbf + (jw + m) * BD + q * 8);
        u32x4 b1 = *(const u32x4*)(tbf + (jw + m) * BD + 32 + q * 8);
        float sj = s[jw + m];
#pragma unroll
        for (int mt = 0; mt < 4; ++mt) {
            f32x4 c = {0.f, 0.f, 0.f, 0.f};
            c = mfma16(afr[mt][0], b0, c);
            c = mfma16(afr[mt][1], b1, c);
#pragma unroll
            for (int r = 0; r < 4; ++r) {
                float a = adj_fn(c[r], si[mt][r] + sj);
                dsum[mt][r] += a;
                Slds[mt * 16 + q * 4 + r][wave * 16 + m] = f2bf(a);
            }
        }
        __syncthreads();
        // store 8 fragments: wave w -> i-tile (i0/16 + w), k-tiles J/32 + {0,1}
#pragma unroll
        for (int ktl = 0; ktl < 2; ++ktl) {
            u32x4 v = *(const u32x4*)(&Slds[wave * 16 + m][ktl * 32 + q * 8]);
            *(u32x4*)(adjF + ((size_t)((i0 >> 4) + wave) * 256 + (J >> 5) + ktl) * 512 + lane * 8) = v;
        }
        __syncthreads();
    }

#pragma unroll
    for (int mt = 0; mt < 4; ++mt)
#pragma unroll
        for (int r = 0; r < 4; ++r) {
            float v = dsum[mt][r];
            v += __shfl_xor(v, 1); v += __shfl_xor(v, 2);
            v += __shfl_xor(v, 4); v += __shfl_xor(v, 8);
            if (m == 0) atomicAdd(&d[i0 + mt * 16 + q * 4 + r], v);
        }
}

// ---------------- dinv ----------------
__global__ void dinv_kernel(const float* __restrict__ d, float* __restrict__ dinv) {
    int i = blockIdx.x * 256 + threadIdx.x;
    dinv[i] = rsqrtf(d[i] + 1e-8f);
}

// ---------------- fc: fcF = frag-major bf16(dinv[i]*(cbnF @ WF + b)) ----------------
// grid (128 iblk, 8): wave w -> nt = by*4 + w. All-frag loads, K=512 (16 ct).
__global__ __launch_bounds__(256) void fc_kernel(const unsigned short* __restrict__ cbnF,
                                                 const unsigned short* __restrict__ WF,
                                                 const float* __restrict__ bias,
                                                 const float* __restrict__ dinv,
                                                 unsigned short* __restrict__ fcF) {
    const int lane = threadIdx.x & 63;
    const int wave = threadIdx.x >> 6;
    const int m = lane & 15, q = lane >> 4;
    const int i0 = blockIdx.x * 64;
    const int ntg = blockIdx.y * 4 + wave;   // 0..31

    const u32x4* Ag = (const u32x4*)cbnF;
    const u32x4* Bg = (const u32x4*)WF;

    f32x4 acc[4] = {};
#pragma unroll
    for (int ct = 0; ct < 16; ++ct) {
        u32x4 bfr = Bg[((size_t)ntg * 16 + ct) * 64 + lane];
#pragma unroll
        for (int mt = 0; mt < 4; ++mt) {
            u32x4 afr = Ag[(((size_t)(i0 >> 4) + mt) * 16 + ct) * 64 + lane];
            acc[mt] = mfma16(afr, bfr, acc[mt]);
        }
    }
    float bv = bias[ntg * 16 + m];
#pragma unroll
    for (int mt = 0; mt < 4; ++mt) {
        int i = i0 + mt * 16 + q * 4;   // conv2 k-index (fc row)
        ushort4 o;
        o.x = f2bf((acc[mt][0] + bv) * dinv[i + 0]);
        o.y = f2bf((acc[mt][1] + bv) * dinv[i + 1]);
        o.z = f2bf((acc[mt][2] + bv) * dinv[i + 2]);
        o.w = f2bf((acc[mt][3] + bv) * dinv[i + 3]);
        // C-layout -> B-frag scatter (verified R5): frag(ntg, i>>5)
        size_t off = ((size_t)ntg * 256 + (i >> 5)) * 512
                   + (size_t)((i >> 3) & 3) * 128 + m * 8 + (q & 1) * 4;
        *(ushort4*)(fcF + off) = o;
    }
}

// ---------------- conv2: out = sigmoid(dvi * (adj @ fc2)) — frag-major GEMM ----------------
// M=8192 N=512 K=8192. Block 64x128, 4 waves (64x32 each), k-chunk 128, dbuf LDS, 1 barrier/chunk.
// Swizzle: xcd = bid&7 (dispatch round-robin); the 4 blocks sharing an A-slice (same iblk,
// cblk 0..3) are consecutive j on the SAME xcd -> co-resident, A-slice served once per XCD L2.
__global__ __launch_bounds__(256) void conv2_kernel(const unsigned short* __restrict__ adjF,
                                                    const unsigned short* __restrict__ fcF,
                                                    const float* __restrict__ dinv,
                                                    float* __restrict__ out) {
    const int bid = blockIdx.x;
    const int xcd = bid & 7;
    const int j = bid >> 3;              // 0..63
    const int iblk = xcd * 16 + (j >> 2);
    const int cblk = j & 3;
    const int i0 = iblk * 64;

    const int lane = threadIdx.x & 63;
    const int wave = threadIdx.x >> 6;   // 0..3
    const int m = lane & 15, q = lane >> 4;
    const int cw = cblk * 128 + wave * 32;
    const int ntb = cw >> 4;

    __shared__ __align__(16) unsigned short Abuf[2][KC / 32][4][512];  // 32 KB identity frag layout

    const u32x4* Ag = (const u32x4*)adjF;
    const u32x4* Bg = (const u32x4*)fcF;
    const int itw = (i0 >> 4) + wave;    // this wave stages mt = wave

    f32x4 acc[4][2] = {};
    u32x4 st[4], bcur[2], bnxt[2];

    // prologue: stage chunk 0, preload B kt 0
#pragma unroll
    for (int ktl = 0; ktl < 4; ++ktl)
        st[ktl] = Ag[((size_t)itw * 256 + ktl) * 64 + lane];
#pragma unroll
    for (int ktl = 0; ktl < 4; ++ktl)
        *(u32x4*)&Abuf[0][ktl][wave][lane * 8] = st[ktl];
    bcur[0] = Bg[((size_t)(ntb + 0) * 256 + 0) * 64 + lane];
    bcur[1] = Bg[((size_t)(ntb + 1) * 256 + 0) * 64 + lane];
    __syncthreads();

    for (int c = 0; c < NN / KC; ++c) {
        const int kb = c * (KC / 32);
        const int cur = c & 1, nxt = cur ^ 1;
        const int kbn = (c + 1 < NN / KC) ? kb + (KC / 32) : kb;
        // A: prefetch next chunk into regs (whole MFMA phase covers latency)
#pragma unroll
        for (int ktl = 0; ktl < 4; ++ktl)
            st[ktl] = Ag[((size_t)itw * 256 + kbn + ktl) * 64 + lane];
        // consume current chunk; B pipelined one kt ahead
#pragma unroll
        for (int ktl = 0; ktl < 4; ++ktl) {
            int ktn = (ktl < 3) ? kb + ktl + 1 : kbn;
            bnxt[0] = Bg[((size_t)(ntb + 0) * 256 + ktn) * 64 + lane];
            bnxt[1] = Bg[((size_t)(ntb + 1) * 256 + ktn) * 64 + lane];
            u32x4 pa[4];
#pragma unroll
            for (int mt = 0; mt < 4; ++mt)
                pa[mt] = *(const u32x4*)&Abuf[cur][ktl][mt][lane * 8];
#pragma unroll
            for (int nt = 0; nt < 2; ++nt)
#pragma unroll
                for (int mt = 0; mt < 4; ++mt)
                    acc[mt][nt] = mfma16(pa[mt], bcur[nt], acc[mt][nt]);
            bcur[0] = bnxt[0]; bcur[1] = bnxt[1];
        }
        // publish next chunk. Safe with one barrier: buf[nxt] was last READ in iter c-1,
        // and every wave passed the barrier at end of c-1 only after finishing those reads.
#pragma unroll
        for (int ktl = 0; ktl < 4; ++ktl)
            *(u32x4*)&Abuf[nxt][ktl][wave][lane * 8] = st[ktl];
        __syncthreads();
    }

#pragma unroll
    for (int mt = 0; mt < 4; ++mt)
#pragma unroll
        for (int r = 0; r < 4; ++r) {
            int row = i0 + mt * 16 + q * 4 + r;
            float dv = dinv[row];
#pragma unroll
            for (int nt = 0; nt < 2; ++nt) {
                float xv = acc[mt][nt][r] * dv;
                out[(size_t)row * CDIM + cw + nt * 16 + m] = 1.0f / (1.0f + __expf(-xv));
            }
        }
}

extern "C" void kernel_launch(void* const* d_in, const int* in_sizes, int n_in,
                              void* d_out, int out_size, void* d_ws, size_t ws_size,
                              hipStream_t stream) {
    const float* bbn = (const float*)d_in[0];
    const float* cbn = (const float*)d_in[1];
    const float* W   = (const float*)d_in[2];
    const float* b   = (const float*)d_in[3];
    float* out = (float*)d_out;  // reference output is float32

    char* ws = (char*)d_ws;
    unsigned short* tbf  = (unsigned short*)(ws);                 // 1 MB
    float* s             = (float*)(ws + (1u << 20));             // 32 KB
    float* d             = (float*)(ws + (1u << 20) + 32768);     // 32 KB
    float* dinv          = (float*)(ws + (1u << 20) + 65536);     // 32 KB
    unsigned short* fcF  = (unsigned short*)(ws + (2u << 20));    // 8 MB
    unsigned short* cbnF = (unsigned short*)(ws + (10u << 20));   // 8 MB
    unsigned short* WF   = (unsigned short*)(ws + (18u << 20));   // 0.5 MB
    unsigned short* adjF = (unsigned short*)(ws + (19u << 20));   // 128 MiB

    prep_kernel<<<NN * 16 / 256, 256, 0, stream>>>(bbn, tbf, s);
    prep_cbn_kernel<<<512, 256, 0, stream>>>(cbn, cbnF);
    prep_w_kernel<<<128, 256, 0, stream>>>(W, WF);
    hipMemsetAsync(d, 0, NN * sizeof(float), stream);
    scoredeg_kernel<<<dim3(NN / 64, 16), 256, 0, stream>>>(tbf, s, d, adjF);
    dinv_kernel<<<NN / 256, 256, 0, stream>>>(d, dinv);
    fc_kernel<<<dim3(NN / 64, 8), 256, 0, stream>>>(cbnF, WF, b, dinv, fcF);
    conv2_kernel<<<512, 256, 0, stream>>>(adjF, fcF, dinv, out);
}

// Round 7
// 206.089 us; speedup vs baseline: 2.4156x; 1.1760x over previous
//
#include <hip/hip_runtime.h>
#include <hip/hip_bf16.h>

// N=8192 rows, BD=64 code dim, CD=512 channel dim
#define NN 8192
#define BD 64
#define CDIM 512

typedef __attribute__((ext_vector_type(4))) float f32x4;
typedef __attribute__((ext_vector_type(4))) unsigned int u32x4;
typedef __attribute__((ext_vector_type(8))) __bf16 bf16x8;

// Fragment-major layouts (elems = unsigned short), frag = 512 ushorts = 1 KB:
//  adjF frag(it,kt): it=i/16 [0,512), kt=k/32 [0,256): off=(it*256+kt)*512+lane*8
//    lane=q*16+m holds adj[it*16+m][kt*32+q*8 .. +7]   (A-operand layout)
//  fcF  frag(nt,kt): nt=n/16 [0,32), kt=k/32 [0,256):  off=(nt*256+kt)*512+lane*8
//    lane holds fc2[kt*32+q*8 .. +7][nt*16+m]          (B-operand layout)
//  cbnF frag(it,ct): off=(it*16+ct)*512+lane*8  (A) ;  WF frag(nt,ct): off=(nt*16+ct)*512+lane*8 (B)

static __device__ __forceinline__ unsigned short f2bf(float x) {
    unsigned int u = __float_as_uint(x);
    u += 0x7fffu + ((u >> 16) & 1u);   // RTNE
    return (unsigned short)(u >> 16);
}

static __device__ __forceinline__ f32x4 mfma16(u32x4 a, u32x4 b, f32x4 c) {
    return __builtin_amdgcn_mfma_f32_16x16x32_bf16(
        __builtin_bit_cast(bf16x8, a), __builtin_bit_cast(bf16x8, b), c, 0, 0, 0);
}

static __device__ __forceinline__ u32x4 cvt8(const float* __restrict__ p) {
    float4 a = *(const float4*)p;
    float4 b = *(const float4*)(p + 4);
    u32x4 r;
    r.x = (unsigned)f2bf(a.x) | ((unsigned)f2bf(a.y) << 16);
    r.y = (unsigned)f2bf(a.z) | ((unsigned)f2bf(a.w) << 16);
    r.z = (unsigned)f2bf(b.x) | ((unsigned)f2bf(b.y) << 16);
    r.w = (unsigned)f2bf(b.z) | ((unsigned)f2bf(b.w) << 16);
    return r;
}

// adj = (max(1 - |2*dot - si - sj|/64, 0))^1.4
static __device__ __forceinline__ float adj_fn(float dot, float sij) {
    float x = fabsf(fmaf(2.0f, dot, -sij));
    float base = fmaxf(fmaf(-0.015625f, x, 1.0f), 0.0f);
    return exp2f(1.4f * __log2f(base));   // pow(0,1.4)=0 via -inf
}

// ---------------- prep: bbn -> bf16 (row-major), row sums s ----------------
__global__ void prep_kernel(const float* __restrict__ bbn,
                            unsigned short* __restrict__ tbf,
                            float* __restrict__ s) {
    int gid = blockIdx.x * blockDim.x + threadIdx.x;  // 16 threads/row
    int row = gid >> 4;
    int part = gid & 15;
    float4 v = *(const float4*)(bbn + row * BD + part * 4);
    ushort4 o;
    o.x = f2bf(v.x); o.y = f2bf(v.y); o.z = f2bf(v.z); o.w = f2bf(v.w);
    *(ushort4*)(tbf + row * BD + part * 4) = o;
    float ps = v.x + v.y + v.z + v.w;
    ps += __shfl_xor(ps, 1); ps += __shfl_xor(ps, 2);
    ps += __shfl_xor(ps, 4); ps += __shfl_xor(ps, 8);
    if (part == 0) s[row] = ps;
}

// ---------------- prep_cbn: cbn -> A-frag-major bf16 ----------------
__global__ __launch_bounds__(256) void prep_cbn_kernel(const float* __restrict__ cbn,
                                                       unsigned short* __restrict__ cbnF) {
    const int lane = threadIdx.x & 63;
    const int wave = threadIdx.x >> 6;
    const int m = lane & 15, q = lane >> 4;
#pragma unroll
    for (int t = 0; t < 4; ++t) {
        int f = blockIdx.x * 16 + wave * 4 + t;   // 8192 frags
        int it = f >> 4, ct = f & 15;
        u32x4 v = cvt8(cbn + (size_t)(it * 16 + m) * CDIM + ct * 32 + q * 8);
        *(u32x4*)(cbnF + (size_t)f * 512 + lane * 8) = v;
    }
}

// ---------------- prep_w: W -> B-frag-major bf16 ----------------
__global__ __launch_bounds__(256) void prep_w_kernel(const float* __restrict__ W,
                                                     unsigned short* __restrict__ WF) {
    const int lane = threadIdx.x & 63;
    const int wave = threadIdx.x >> 6;
    const int m = lane & 15, q = lane >> 4;
    int f = blockIdx.x * 4 + wave;   // 512 frags
    int nt = f >> 4, ct = f & 15;
    u32x4 v = cvt8(W + (size_t)(nt * 16 + m) * CDIM + ct * 32 + q * 8);
    *(u32x4*)(WF + (size_t)f * 512 + lane * 8) = v;
}

// ---------------- scoredeg: adjF = frag-major bf16 adj, d[i] = row sums ----------------
// grid (128 i-tiles, 16 j-chunks of 512) = 2048 blocks -> 8 blocks/CU.
// Double-buffered LDS: ONE barrier per 64-j tile (write p | barrier | read p || write p^1 ...).
__global__ __launch_bounds__(256) void scoredeg_kernel(const unsigned short* __restrict__ tbf,
                                                       const float* __restrict__ s,
                                                       float* __restrict__ d,
                                                       unsigned short* __restrict__ adjF) {
    const int lane = threadIdx.x & 63;
    const int wave = threadIdx.x >> 6;   // 0..3
    const int m = lane & 15, q = lane >> 4;
    const int i0 = blockIdx.x * 64;
    const int jbase = blockIdx.y * 512;

    __shared__ __align__(16) unsigned short Slds[2][64][72];  // 18.4 KB

    u32x4 afr[4][2];
    float si[4][4];
#pragma unroll
    for (int mt = 0; mt < 4; ++mt) {
#pragma unroll
        for (int ks = 0; ks < 2; ++ks)
            afr[mt][ks] = *(const u32x4*)(tbf + (i0 + mt * 16 + m) * BD + ks * 32 + q * 8);
#pragma unroll
        for (int r = 0; r < 4; ++r) si[mt][r] = s[i0 + mt * 16 + q * 4 + r];
    }
    float dsum[4][4] = {};

    // prefetch iter-0 B operand
    int jw = jbase + wave * 16;
    u32x4 b0 = *(const u32x4*)(tbf + (jw + m) * BD + q * 8);
    u32x4 b1 = *(const u32x4*)(tbf + (jw + m) * BD + 32 + q * 8);
    float sj = s[jw + m];

    for (int it8 = 0; it8 < 8; ++it8) {
        const int J = jbase + it8 * 64;
        const int p = it8 & 1;
        f32x4 c[4];
#pragma unroll
        for (int mt = 0; mt < 4; ++mt) {
            c[mt] = f32x4{0.f, 0.f, 0.f, 0.f};
            c[mt] = mfma16(afr[mt][0], b0, c[mt]);
            c[mt] = mfma16(afr[mt][1], b1, c[mt]);
        }
        // prefetch next iter's B while transform runs
        int jn = (it8 < 7) ? J + 64 + wave * 16 : jbase + wave * 16;
        u32x4 nb0 = *(const u32x4*)(tbf + (jn + m) * BD + q * 8);
        u32x4 nb1 = *(const u32x4*)(tbf + (jn + m) * BD + 32 + q * 8);
        float nsj = s[jn + m];
#pragma unroll
        for (int mt = 0; mt < 4; ++mt)
#pragma unroll
            for (int r = 0; r < 4; ++r) {
                float a = adj_fn(c[mt][r], si[mt][r] + sj);
                dsum[mt][r] += a;
                Slds[p][mt * 16 + q * 4 + r][wave * 16 + m] = f2bf(a);
            }
        __syncthreads();
        // frag store: wave w -> it-tile (i0/16 + w), k-tiles J/32 + {0,1}
#pragma unroll
        for (int ktl = 0; ktl < 2; ++ktl) {
            u32x4 v = *(const u32x4*)(&Slds[p][wave * 16 + m][ktl * 32 + q * 8]);
            *(u32x4*)(adjF + ((size_t)((i0 >> 4) + wave) * 256 + (J >> 5) + ktl) * 512 + lane * 8) = v;
        }
        b0 = nb0; b1 = nb1; sj = nsj;
    }

#pragma unroll
    for (int mt = 0; mt < 4; ++mt)
#pragma unroll
        for (int r = 0; r < 4; ++r) {
            float v = dsum[mt][r];
            v += __shfl_xor(v, 1); v += __shfl_xor(v, 2);
            v += __shfl_xor(v, 4); v += __shfl_xor(v, 8);
            if (m == 0) atomicAdd(&d[i0 + mt * 16 + q * 4 + r], v);
        }
}

// ---------------- dinv ----------------
__global__ void dinv_kernel(const float* __restrict__ d, float* __restrict__ dinv) {
    int i = blockIdx.x * 256 + threadIdx.x;
    dinv[i] = rsqrtf(d[i] + 1e-8f);
}

// ---------------- fc: fcF = frag-major bf16(dinv[i]*(cbnF @ WF + b)) ----------------
__global__ __launch_bounds__(256) void fc_kernel(const unsigned short* __restrict__ cbnF,
                                                 const unsigned short* __restrict__ WF,
                                                 const float* __restrict__ bias,
                                                 const float* __restrict__ dinv,
                                                 unsigned short* __restrict__ fcF) {
    const int lane = threadIdx.x & 63;
    const int wave = threadIdx.x >> 6;
    const int m = lane & 15, q = lane >> 4;
    const int i0 = blockIdx.x * 64;
    const int ntg = blockIdx.y * 4 + wave;   // 0..31

    const u32x4* Ag = (const u32x4*)cbnF;
    const u32x4* Bg = (const u32x4*)WF;

    f32x4 acc[4] = {};
#pragma unroll
    for (int ct = 0; ct < 16; ++ct) {
        u32x4 bfr = Bg[((size_t)ntg * 16 + ct) * 64 + lane];
#pragma unroll
        for (int mt = 0; mt < 4; ++mt) {
            u32x4 afr = Ag[(((size_t)(i0 >> 4) + mt) * 16 + ct) * 64 + lane];
            acc[mt] = mfma16(afr, bfr, acc[mt]);
        }
    }
    float bv = bias[ntg * 16 + m];
#pragma unroll
    for (int mt = 0; mt < 4; ++mt) {
        int i = i0 + mt * 16 + q * 4;   // conv2 k-index (fc row)
        ushort4 o;
        o.x = f2bf((acc[mt][0] + bv) * dinv[i + 0]);
        o.y = f2bf((acc[mt][1] + bv) * dinv[i + 1]);
        o.z = f2bf((acc[mt][2] + bv) * dinv[i + 2]);
        o.w = f2bf((acc[mt][3] + bv) * dinv[i + 3]);
        size_t off = ((size_t)ntg * 256 + (i >> 5)) * 512
                   + (size_t)((i >> 3) & 3) * 128 + m * 8 + (q & 1) * 4;
        *(ushort4*)(fcF + off) = o;
    }
}

// ---------------- conv2: out = sigmoid(dvi * (adj @ fc2)) — frag-major GEMM ----------------
// M=8192 N=512 K=8192. Block 128 rows x 128 cols, 512 thr / 8 waves; wave = 16-col slice
// spanning all 128 rows (acc 8 frags). K-chunk 128 in dbuf LDS (64 KB), 1 barrier/chunk.
// B prefetched 4 kt deep (620 cyc MFMA cover >= L3 latency).
// Swizzle: 256 blocks, xcd=bid&7; iblk=(g>>2)*8+xcd -> the 4 cblk blocks of an iblk are
// co-resident on ONE xcd => A slice fetched from HBM once, L2 serves re-reads.
__global__ __launch_bounds__(512) void conv2_kernel(const unsigned short* __restrict__ adjF,
                                                    const unsigned short* __restrict__ fcF,
                                                    const float* __restrict__ dinv,
                                                    float* __restrict__ out) {
    const int bid = blockIdx.x;
    const int xcd = bid & 7;
    const int g = bid >> 3;               // 0..31
    const int iblk = (g >> 2) * 8 + xcd;  // 0..63
    const int cblk = g & 3;
    const int i0 = iblk * 128;

    const int lane = threadIdx.x & 63;
    const int wave = threadIdx.x >> 6;    // 0..7
    const int m = lane & 15, q = lane >> 4;
    const int nt = cblk * 8 + wave;       // 0..31: this wave's 16 output cols

    __shared__ __align__(16) unsigned short Abuf[2][4][8][512];  // 64 KB [buf][ktl][it][frag]

    const u32x4* Ag = (const u32x4*)adjF;
    const u32x4* Bg = (const u32x4*)fcF;
    const int itw = (i0 >> 4) + wave;     // wave stages it-tile = wave

    f32x4 acc[8] = {};
    u32x4 st[4], bq[4];

    // prologue: stage chunk 0, preload B kt 0..3
#pragma unroll
    for (int ktl = 0; ktl < 4; ++ktl)
        st[ktl] = Ag[((size_t)itw * 256 + ktl) * 64 + lane];
#pragma unroll
    for (int ktl = 0; ktl < 4; ++ktl)
        *(u32x4*)&Abuf[0][ktl][wave][lane * 8] = st[ktl];
#pragma unroll
    for (int ktl = 0; ktl < 4; ++ktl)
        bq[ktl] = Bg[((size_t)nt * 256 + ktl) * 64 + lane];
    __syncthreads();

    for (int c = 0; c < 64; ++c) {
        const int kb = c * 4;
        const int cur = c & 1, nxt = cur ^ 1;
        const int kbn = (c < 63) ? kb + 4 : kb;
        // A: prefetch next chunk into regs (whole MFMA phase covers HBM latency)
#pragma unroll
        for (int ktl = 0; ktl < 4; ++ktl)
            st[ktl] = Ag[((size_t)itw * 256 + kbn + ktl) * 64 + lane];
#pragma unroll
        for (int ktl = 0; ktl < 4; ++ktl) {
            int ktn = kb + ktl + 4; if (ktn > 255) ktn = 255;
            u32x4 bn = Bg[((size_t)nt * 256 + ktn) * 64 + lane];
            u32x4 pa[8];
#pragma unroll
            for (int mt = 0; mt < 8; ++mt)
                pa[mt] = *(const u32x4*)&Abuf[cur][ktl][mt][lane * 8];
#pragma unroll
            for (int mt = 0; mt < 8; ++mt)
                acc[mt] = mfma16(pa[mt], bq[ktl], acc[mt]);
            bq[ktl] = bn;
        }
        // publish next chunk (safe: buf[nxt] last read in c-1, barrier since)
#pragma unroll
        for (int ktl = 0; ktl < 4; ++ktl)
            *(u32x4*)&Abuf[nxt][ktl][wave][lane * 8] = st[ktl];
        __syncthreads();
    }

#pragma unroll
    for (int mt = 0; mt < 8; ++mt)
#pragma unroll
        for (int r = 0; r < 4; ++r) {
            int row = i0 + mt * 16 + q * 4 + r;
            float dv = dinv[row];
            float xv = acc[mt][r] * dv;
            out[(size_t)row * CDIM + cblk * 128 + wave * 16 + m] = 1.0f / (1.0f + __expf(-xv));
        }
}

extern "C" void kernel_launch(void* const* d_in, const int* in_sizes, int n_in,
                              void* d_out, int out_size, void* d_ws, size_t ws_size,
                              hipStream_t stream) {
    const float* bbn = (const float*)d_in[0];
    const float* cbn = (const float*)d_in[1];
    const float* W   = (const float*)d_in[2];
    const float* b   = (const float*)d_in[3];
    float* out = (float*)d_out;  // reference output is float32

    char* ws = (char*)d_ws;
    unsigned short* tbf  = (unsigned short*)(ws);                 // 1 MB
    float* s             = (float*)(ws + (1u << 20));             // 32 KB
    float* d             = (float*)(ws + (1u << 20) + 32768);     // 32 KB
    float* dinv          = (float*)(ws + (1u << 20) + 65536);     // 32 KB
    unsigned short* fcF  = (unsigned short*)(ws + (2u << 20));    // 8 MB
    unsigned short* cbnF = (unsigned short*)(ws + (10u << 20));   // 8 MB
    unsigned short* WF   = (unsigned short*)(ws + (18u << 20));   // 0.5 MB
    unsigned short* adjF = (unsigned short*)(ws + (19u << 20));   // 128 MiB

    prep_kernel<<<NN * 16 / 256, 256, 0, stream>>>(bbn, tbf, s);
    prep_cbn_kernel<<<512, 256, 0, stream>>>(cbn, cbnF);
    prep_w_kernel<<<128, 256, 0, stream>>>(W, WF);
    hipMemsetAsync(d, 0, NN * sizeof(float), stream);
    scoredeg_kernel<<<dim3(NN / 64, 16), 256, 0, stream>>>(tbf, s, d, adjF);
    dinv_kernel<<<NN / 256, 256, 0, stream>>>(d, dinv);
    fc_kernel<<<dim3(NN / 64, 8), 256, 0, stream>>>(cbnF, WF, b, dinv, fcF);
    conv2_kernel<<<256, 512, 0, stream>>>(adjF, fcF, dinv, out);
}